// Round 12
// baseline (232.449 us; speedup 1.0000x reference)
//
#include <hip/hip_runtime.h>
#include <hip/hip_bf16.h>
#include <math.h>

#define B 16
#define N 1024
#define F_IN 80
#define D 64
#define DEPTH 4
#define BN_EPS 1e-5f

typedef __attribute__((ext_vector_type(8))) short  short8v;
typedef __attribute__((ext_vector_type(4))) float  float4v;

union AFrag { unsigned int u[4]; short8v s; };

__device__ __forceinline__ unsigned short f2bf_rne(float x) {
    unsigned int u = __float_as_uint(x);
    unsigned int r = u + 0x7FFFu + ((u >> 16) & 1u);
    return (unsigned short)(r >> 16);
}
__device__ __forceinline__ float bf2f(unsigned short b) {
    return __uint_as_float(((unsigned int)b) << 16);
}
// trunc-split a pair of positives into packed bf16 hi / residual-lo words.
// |w - (hi+lo)| <= 2^-17 * w
__device__ __forceinline__ void split_pair(float w0, float w1,
                                           unsigned int& hi, unsigned int& lo) {
    unsigned int u0 = __float_as_uint(w0), u1 = __float_as_uint(w1);
    unsigned int h0 = u0 & 0xFFFF0000u,   h1 = u1 & 0xFFFF0000u;
    hi = (h0 >> 16) | h1;
    float r0 = w0 - __uint_as_float(h0);
    float r1 = w1 - __uint_as_float(h1);
    lo = (__float_as_uint(r0) >> 16) | (__float_as_uint(r1) & 0xFFFF0000u);
}

// ---------------- adj bit-pack: each thread 16 ints -> one u16 store ----------------
__global__ __launch_bounds__(256) void k_pack(const int* __restrict__ adj,
                                              unsigned short* __restrict__ packS) {
    int gid = blockIdx.x * 256 + threadIdx.x;      // 0 .. B*N*N/16-1
    const int4* ap = (const int4*)adj + (size_t)gid * 4;
    unsigned int m = 0;
#pragma unroll
    for (int i = 0; i < 4; ++i) {
        int4 v = ap[i];
        m |= (unsigned int)(v.x > 0) << (i * 4 + 0);
        m |= (unsigned int)(v.y > 0) << (i * 4 + 1);
        m |= (unsigned int)(v.z > 0) << (i * 4 + 2);
        m |= (unsigned int)(v.w > 0) << (i * 4 + 3);
    }
    packS[gid] = (unsigned short)m;
}

// ---------------- h = relu(X @ W0), 16 rows/block ----------------
__global__ __launch_bounds__(256) void k_h0(const float* __restrict__ X,
                                            const float* __restrict__ W0,
                                            float* __restrict__ h) {
    int b = blockIdx.x >> 6, n0 = (blockIdx.x & 63) << 4;
    int t = threadIdx.x;
    __shared__ float w0s[F_IN * D];   // 20KB
    __shared__ float xs[16 * F_IN];   // 5KB
    for (int j = t; j < F_IN * D / 4; j += 256)
        ((float4*)w0s)[j] = ((const float4*)W0)[j];
    const float* xp = X + ((size_t)(b * N + n0)) * F_IN;
    for (int j = t; j < 16 * F_IN / 4; j += 256)
        ((float4*)xs)[j] = ((const float4*)xp)[j];
    __syncthreads();
    int d = t & 63, wid = t >> 6;
    float acc[4] = {0.f, 0.f, 0.f, 0.f};
    for (int f = 0; f < F_IN; ++f) {
        float wv = w0s[f * D + d];
#pragma unroll
        for (int j = 0; j < 4; ++j) acc[j] += xs[(wid * 4 + j) * F_IN + f] * wv;
    }
    float* hp = h + ((size_t)(b * N + n0 + wid * 4)) * D + d;
#pragma unroll
    for (int j = 0; j < 4; ++j) hp[(size_t)j * D] = fmaxf(acc[j], 0.f);
}

// ---------------- hW = relu(h@Wl) -> bf16 hi/lo planes in B-frag order; t1,t2 ----------------
__global__ __launch_bounds__(256) void k_hw(const float* __restrict__ h,
                                            const float* __restrict__ Wl,
                                            const float* __restrict__ a1,
                                            const float* __restrict__ a2,
                                            unsigned short* __restrict__ hWhi,
                                            unsigned short* __restrict__ hWlo,
                                            float* __restrict__ t1,
                                            float* __restrict__ t2) {
    int b = blockIdx.x >> 6, n0 = (blockIdx.x & 63) << 4;
    int t = threadIdx.x;
    __shared__ float wls[D * D];   // 16KB
    __shared__ float hs[16 * D];   // 4KB
    for (int j = t; j < D * D / 4; j += 256)
        ((float4*)wls)[j] = ((const float4*)Wl)[j];
    const float* hp = h + ((size_t)(b * N + n0)) * D;
    if (t < 16 * D / 4) ((float4*)hs)[t] = ((const float4*)hp)[t];
    __syncthreads();
    int d = t & 63, wid = t >> 6;
    float acc[4] = {0.f, 0.f, 0.f, 0.f};
    for (int k = 0; k < D; ++k) {
        float wv = wls[k * D + d];
#pragma unroll
        for (int j = 0; j < 4; ++j) acc[j] += hs[(wid * 4 + j) * D + k] * wv;
    }
    float a1d = a1[d], a2d = a2[d];

    float v[4];
    unsigned short vh[4], vl[4];
#pragma unroll
    for (int j = 0; j < 4; ++j) {
        v[j] = fmaxf(acc[j], 0.f);
        vh[j] = f2bf_rne(v[j]);
        vl[j] = f2bf_rne(v[j] - bf2f(vh[j]));
    }
    {
        int m0 = n0 + wid * 4;
        int kb = m0 >> 5, i0 = m0 & 7;
        int lb = ((m0 >> 3) & 3) * 16 + (d & 15), dt = d >> 4;
        size_t off = ((size_t)b * (N * D)) + ((kb * 4 + dt) * 64 + lb) * 8 + i0;
        uint2 hpack, lpack;
        hpack.x = (unsigned int)vh[0] | ((unsigned int)vh[1] << 16);
        hpack.y = (unsigned int)vh[2] | ((unsigned int)vh[3] << 16);
        lpack.x = (unsigned int)vl[0] | ((unsigned int)vl[1] << 16);
        lpack.y = (unsigned int)vl[2] | ((unsigned int)vl[3] << 16);
        *(uint2*)(hWhi + off) = hpack;
        *(uint2*)(hWlo + off) = lpack;
    }
#pragma unroll
    for (int j = 0; j < 4; ++j) {
        float p1 = v[j] * a1d, p2 = v[j] * a2d;
#pragma unroll
        for (int o = 32; o > 0; o >>= 1) {
            p1 += __shfl_down(p1, o);
            p2 += __shfl_down(p2, o);
        }
        if (d == 0) { t1[b * N + n0 + wid * 4 + j] = p1; t2[b * N + n0 + wid * 4 + j] = p2; }
    }
}

// ---------------- fused attention: 16 rows/block, w born in A-frag regs ----------------
// launch_bounds (256,3): the (256,4)=128-VGPR cap forced scratch spill (R11 theory);
// 3 waves/EU raises the cap to ~168 VGPR which fits the ~130-170 estimate.
__global__ __launch_bounds__(256, 3) void k_att(
    const unsigned short* __restrict__ hWhi, const unsigned short* __restrict__ hWlo,
    const float* __restrict__ t1, const float* __restrict__ t2,
    const unsigned long long* __restrict__ packA,
    const float* __restrict__ root_list, int ridx, float* __restrict__ h)
{
    int vb = (blockIdx.x & 7) * 128 + (blockIdx.x >> 3);   // XCD swizzle (1024 blocks)
    int b  = vb >> 6;
    int n0 = (vb & 63) << 4;
    int t = threadIdx.x, lane = t & 63, wid = t >> 6;

    __shared__ float t2s[N];               // 4KB
    __shared__ float redsum[4][16];
    __shared__ float invs[16];
    __shared__ float4v part[4][4][64];     // 16KB: [wid][dt][lane]

    ((float4v*)t2s)[t] = ((const float4v*)(t2 + b * N))[t];
    __syncthreads();

    int r  = lane & 15;
    int qg = wid * 4 + (lane >> 4);        // 0..15: global k-subgroup within a pass
    int n  = n0 + r;
    float t1v = t1[b * N + n];
    const unsigned long long* prow = packA + ((size_t)(b * N + n)) * 16;
    const short8v* BH = (const short8v*)(hWhi + (size_t)b * (N * D));
    const short8v* BL = (const short8v*)(hWlo + (size_t)b * (N * D));

    float4v acc0 = {0,0,0,0}, acc1 = {0,0,0,0}, acc2 = {0,0,0,0}, acc3 = {0,0,0,0};
    float lsum = 0.f;

#pragma unroll 2   // cap unroll: full 8x hoists 64 B-loads -> VGPR blowup
    for (int p = 0; p < 8; ++p) {
        int kb = p * 4 + wid;              // this wave's 32-wide k-block
        int bi = (kb * 4) * 64 + lane;
        short8v bh0 = BH[bi], bh1 = BH[bi + 64], bh2 = BH[bi + 128], bh3 = BH[bi + 192];
        short8v bl0 = BL[bi], bl1 = BL[bi + 64], bl2 = BL[bi + 128], bl3 = BL[bi + 192];

        unsigned long long word = prow[p * 2 + (qg >> 3)];
        unsigned int mbyte = (unsigned int)(word >> ((qg & 7) * 8)) & 0xFFu;

        const float* t2p = t2s + p * 128 + qg * 8;
        float4v ta = ((const float4v*)t2p)[0];
        float4v tb = ((const float4v*)t2p)[1];

        float wv[8];
#pragma unroll
        for (int i = 0; i < 8; ++i) {
            float t2v = (i < 4) ? ta[i & 3] : tb[i & 3];
            float e = ((mbyte >> i) & 1u) ? fmaxf(t1v + t2v, 0.f) : 0.f;
            float w = __expf(e);
            wv[i] = w;
            lsum += w;
        }

        AFrag fh, fl;
#pragma unroll
        for (int i = 0; i < 4; ++i)
            split_pair(wv[2 * i], wv[2 * i + 1], fh.u[i], fl.u[i]);

        acc0 = __builtin_amdgcn_mfma_f32_16x16x32_bf16(fh.s, bh0, acc0, 0, 0, 0);
        acc0 = __builtin_amdgcn_mfma_f32_16x16x32_bf16(fh.s, bl0, acc0, 0, 0, 0);
        acc0 = __builtin_amdgcn_mfma_f32_16x16x32_bf16(fl.s, bh0, acc0, 0, 0, 0);
        acc1 = __builtin_amdgcn_mfma_f32_16x16x32_bf16(fh.s, bh1, acc1, 0, 0, 0);
        acc1 = __builtin_amdgcn_mfma_f32_16x16x32_bf16(fh.s, bl1, acc1, 0, 0, 0);
        acc1 = __builtin_amdgcn_mfma_f32_16x16x32_bf16(fl.s, bh1, acc1, 0, 0, 0);
        acc2 = __builtin_amdgcn_mfma_f32_16x16x32_bf16(fh.s, bh2, acc2, 0, 0, 0);
        acc2 = __builtin_amdgcn_mfma_f32_16x16x32_bf16(fh.s, bl2, acc2, 0, 0, 0);
        acc2 = __builtin_amdgcn_mfma_f32_16x16x32_bf16(fl.s, bh2, acc2, 0, 0, 0);
        acc3 = __builtin_amdgcn_mfma_f32_16x16x32_bf16(fh.s, bh3, acc3, 0, 0, 0);
        acc3 = __builtin_amdgcn_mfma_f32_16x16x32_bf16(fh.s, bl3, acc3, 0, 0, 0);
        acc3 = __builtin_amdgcn_mfma_f32_16x16x32_bf16(fl.s, bh3, acc3, 0, 0, 0);
    }

    // per-row softmax denominators: lanes {l, l^16, l^32, l^48} share a row
    lsum += __shfl_xor(lsum, 16);
    lsum += __shfl_xor(lsum, 32);
    if (lane < 16) redsum[wid][lane] = lsum;

    part[wid][0][lane] = acc0;
    part[wid][1][lane] = acc1;
    part[wid][2][lane] = acc2;
    part[wid][3][lane] = acc3;
    __syncthreads();
    if (t < 16) invs[t] = 1.0f / (redsum[0][t] + redsum[1][t] + redsum[2][t] + redsum[3][t]);
    __syncthreads();

    // reduce 4 wave-partials; C mapping: col=lane&15, row=(lane>>4)*4+reg
    int c = t & 63, rg = t >> 6;
    int ls = rg * 16 + (c & 15), dt = c >> 4;
    float4v s = part[0][dt][ls] + part[1][dt][ls] + part[2][dt][ls] + part[3][dt][ls];
    const float* rl = root_list + ((size_t)b * DEPTH + ridx) * N;
#pragma unroll
    for (int reg = 0; reg < 4; ++reg) {
        int rr = rg * 4 + reg;
        if (rl[n0 + rr] > 0.f)
            h[((size_t)(b * N + n0 + rr)) * D + c] = s[reg] * invs[rr];
    }
}

// ---------------- pooling dot: w[b][n] = root>0 ? relu(h.P) : -9e15 ----------------
__global__ __launch_bounds__(256) void k_dotw(const float* __restrict__ h,
                                              const float* __restrict__ root_list,
                                              const float* __restrict__ P,
                                              float* __restrict__ wg) {
    int b = blockIdx.x >> 4, n0 = (blockIdx.x & 15) << 6;
    int t = threadIdx.x;
    int r = n0 + (t >> 2), sub = t & 3;
    const float4* hp = (const float4*)(h + ((size_t)(b * N + r)) * D + sub * 16);
    const float4* pp = (const float4*)(P + sub * 16);
    float s = 0.f;
#pragma unroll
    for (int i = 0; i < 4; ++i) {
        float4 hv = hp[i], pv = pp[i];
        s += hv.x * pv.x + hv.y * pv.y + hv.z * pv.z + hv.w * pv.w;
    }
    s += __shfl_xor(s, 1);
    s += __shfl_xor(s, 2);
    if (sub == 0) {
        float rv = root_list[((size_t)b * DEPTH + 1) * N + r];
        wg[b * N + r] = (rv > 0.f) ? fmaxf(s, 0.f) : -9e15f;
    }
}

// ---------------- softmax + weighted sum + BN-MLP, 1024 threads/batch ----------------
__global__ __launch_bounds__(1024) void k_pool2(const float* __restrict__ h,
                       const float* __restrict__ wg,
                       const float* __restrict__ pW1, const float* __restrict__ pb1,
                       const float* __restrict__ g1, const float* __restrict__ be1,
                       const float* __restrict__ m1, const float* __restrict__ v1,
                       const float* __restrict__ pW2, const float* __restrict__ pb2,
                       const float* __restrict__ g2, const float* __restrict__ be2,
                       const float* __restrict__ m2, const float* __restrict__ v2,
                       const float* __restrict__ pW3, const float* __restrict__ pb3,
                       float* __restrict__ out) {
    int b = blockIdx.x, t = threadIdx.x, lane = t & 63, wid = t >> 6;  // 16 waves
    __shared__ float ws[N];
    __shared__ float red[16];
    __shared__ float part[16][D];
    __shared__ float od[D];
    __shared__ float x1[128];
    __shared__ float x2[64];
    __shared__ float lg[2];

    const float* hb = h + (size_t)b * N * D;
    float sc = wg[b * N + t];

    float lmax = sc;
#pragma unroll
    for (int o = 32; o > 0; o >>= 1) lmax = fmaxf(lmax, __shfl_xor(lmax, o));
    if (lane == 0) red[wid] = lmax;
    __syncthreads();
    float bmax = red[0];
#pragma unroll
    for (int k = 1; k < 16; ++k) bmax = fmaxf(bmax, red[k]);
    __syncthreads();

    float e = __expf(sc - bmax);
    ws[t] = e;
    float lsumv = e;
#pragma unroll
    for (int o = 32; o > 0; o >>= 1) lsumv += __shfl_xor(lsumv, o);
    if (lane == 0) red[wid] = lsumv;
    __syncthreads();
    float bsum = 0.f;
#pragma unroll
    for (int k = 0; k < 16; ++k) bsum += red[k];
    float inv = 1.0f / bsum;

    float acc = 0.f;
    for (int n = wid * 64; n < wid * 64 + 64; ++n) acc += ws[n] * hb[(size_t)n * D + lane];
    part[wid][lane] = acc;
    __syncthreads();
    if (t < D) {
        float s = 0.f;
#pragma unroll
        for (int k = 0; k < 16; ++k) s += part[k][t];
        od[t] = s * inv;
    }
    __syncthreads();

    if (t < 128) {
        float s = pb1[t];
#pragma unroll
        for (int k = 0; k < D; ++k) s += od[k] * pW1[k * 128 + t];
        s = (s - m1[t]) * rsqrtf(v1[t] + BN_EPS) * g1[t] + be1[t];
        x1[t] = fmaxf(s, 0.f);
    }
    __syncthreads();
    if (t < 64) {
        float s = pb2[t];
#pragma unroll
        for (int k = 0; k < 128; ++k) s += x1[k] * pW2[k * 64 + t];
        s = (s - m2[t]) * rsqrtf(v2[t] + BN_EPS) * g2[t] + be2[t];
        x2[t] = fmaxf(s, 0.f);
    }
    __syncthreads();
    if (t < 2) {
        float s = pb3[t];
#pragma unroll
        for (int k = 0; k < 64; ++k) s += x2[k] * pW3[k * 2 + t];
        lg[t] = fmaxf(s, 0.f);
    }
    __syncthreads();
    if (t < 2) {
        float mm = fmaxf(lg[0], lg[1]);
        float e0 = __expf(lg[0] - mm), e1 = __expf(lg[1] - mm);
        out[b * 2 + t] = ((t == 0) ? e0 : e1) / (e0 + e1);
    }
}

extern "C" void kernel_launch(void* const* d_in, const int* in_sizes, int n_in,
                              void* d_out, int out_size, void* d_ws, size_t ws_size,
                              hipStream_t stream) {
    const int*   adj = (const int*)d_in[0];
    const float* X   = (const float*)d_in[1];
    const float* rl  = (const float*)d_in[2];
    const float* W0  = (const float*)d_in[3];
    const float* Wl  = (const float*)d_in[4];
    const float* a1l = (const float*)d_in[5];
    const float* a2l = (const float*)d_in[6];
    const float* P   = (const float*)d_in[7];
    const float* pW1 = (const float*)d_in[8];
    const float* pb1 = (const float*)d_in[9];
    const float* g1  = (const float*)d_in[10];
    const float* be1 = (const float*)d_in[11];
    const float* m1  = (const float*)d_in[12];
    const float* v1  = (const float*)d_in[13];
    const float* pW2 = (const float*)d_in[14];
    const float* pb2 = (const float*)d_in[15];
    const float* g2  = (const float*)d_in[16];
    const float* be2 = (const float*)d_in[17];
    const float* m2  = (const float*)d_in[18];
    const float* v2  = (const float*)d_in[19];
    const float* pW3 = (const float*)d_in[20];
    const float* pb3 = (const float*)d_in[21];
    float* out = (float*)d_out;

    // ws layout: 10,616,832 B total — footprint proven since R3
    float*          h    = (float*)d_ws;                                   // 4MB
    unsigned short* hWhi = (unsigned short*)(h + (size_t)B * N * D);       // 2MB
    unsigned short* hWlo = hWhi + (size_t)B * N * D;                       // 2MB
    float*          t1   = (float*)(hWlo + (size_t)B * N * D);             // 64KB
    float*          t2   = t1 + B * N;                                     // 64KB
    unsigned long long* packA = (unsigned long long*)(t2 + B * N);         // 2MB
    float*          wg   = t1;   // t1 dead after layer loop; reuse for pooling scores

    k_pack<<<B * N * N / 16 / 256, 256, 0, stream>>>(adj, (unsigned short*)packA);
    k_h0<<<B * 64, 256, 0, stream>>>(X, W0, h);
    for (int i = 0; i < DEPTH - 1; ++i) {
        k_hw<<<B * 64, 256, 0, stream>>>(h, Wl + i * D * D, a1l + i * D, a2l + i * D,
                                         hWhi, hWlo, t1, t2);
        k_att<<<B * 64, 256, 0, stream>>>(hWhi, hWlo, t1, t2, packA, rl,
                                          DEPTH - 1 - i, h);
    }
    k_dotw<<<B * 16, 256, 0, stream>>>(h, rl, P, wg);
    k_pool2<<<B, 1024, 0, stream>>>(h, wg, pW1, pb1, g1, be1, m1, v1,
                                    pW2, pb2, g2, be2, m2, v2, pW3, pb3, out);
}

// Round 13
// 227.066 us; speedup vs baseline: 1.0237x; 1.0237x over previous
//
#include <hip/hip_runtime.h>
#include <hip/hip_bf16.h>
#include <math.h>

#define B 16
#define N 1024
#define F_IN 80
#define D 64
#define DEPTH 4
#define BN_EPS 1e-5f

typedef __attribute__((ext_vector_type(8))) short  short8v;
typedef __attribute__((ext_vector_type(4))) float  float4v;

union AFrag { unsigned int u[4]; short8v s; };

__device__ __forceinline__ unsigned short f2bf_rne(float x) {
    unsigned int u = __float_as_uint(x);
    unsigned int r = u + 0x7FFFu + ((u >> 16) & 1u);
    return (unsigned short)(r >> 16);
}
__device__ __forceinline__ float bf2f(unsigned short b) {
    return __uint_as_float(((unsigned int)b) << 16);
}
// trunc-split a pair of positives into packed bf16 hi / residual-lo words.
// |w - (hi+lo)| <= 2^-17 * w
__device__ __forceinline__ void split_pair(float w0, float w1,
                                           unsigned int& hi, unsigned int& lo) {
    unsigned int u0 = __float_as_uint(w0), u1 = __float_as_uint(w1);
    unsigned int h0 = u0 & 0xFFFF0000u,   h1 = u1 & 0xFFFF0000u;
    hi = (h0 >> 16) | h1;
    float r0 = w0 - __uint_as_float(h0);
    float r1 = w1 - __uint_as_float(h1);
    lo = (__float_as_uint(r0) >> 16) | (__float_as_uint(r1) & 0xFFFF0000u);
}

// ---------------- fused: adj bit-pack (blocks 0..4095) + h0 (blocks 4096..5119) ----------------
__global__ __launch_bounds__(256) void k_pre(const int* __restrict__ adj,
                                             unsigned short* __restrict__ packS,
                                             const float* __restrict__ X,
                                             const float* __restrict__ W0,
                                             float* __restrict__ h) {
    if (blockIdx.x < 4096) {
        int gid = blockIdx.x * 256 + threadIdx.x;      // 0 .. B*N*N/16-1
        const int4* ap = (const int4*)adj + (size_t)gid * 4;
        unsigned int m = 0;
#pragma unroll
        for (int i = 0; i < 4; ++i) {
            int4 v = ap[i];
            m |= (unsigned int)(v.x > 0) << (i * 4 + 0);
            m |= (unsigned int)(v.y > 0) << (i * 4 + 1);
            m |= (unsigned int)(v.z > 0) << (i * 4 + 2);
            m |= (unsigned int)(v.w > 0) << (i * 4 + 3);
        }
        packS[gid] = (unsigned short)m;
        return;
    }
    int bid = blockIdx.x - 4096;
    int b = bid >> 6, n0 = (bid & 63) << 4;
    int t = threadIdx.x;
    __shared__ float w0s[F_IN * D];   // 20KB
    __shared__ float xs[16 * F_IN];   // 5KB
    for (int j = t; j < F_IN * D / 4; j += 256)
        ((float4*)w0s)[j] = ((const float4*)W0)[j];
    const float* xp = X + ((size_t)(b * N + n0)) * F_IN;
    for (int j = t; j < 16 * F_IN / 4; j += 256)
        ((float4*)xs)[j] = ((const float4*)xp)[j];
    __syncthreads();
    int d = t & 63, wid = t >> 6;
    float acc[4] = {0.f, 0.f, 0.f, 0.f};
    for (int f = 0; f < F_IN; ++f) {
        float wv = w0s[f * D + d];
#pragma unroll
        for (int j = 0; j < 4; ++j) acc[j] += xs[(wid * 4 + j) * F_IN + f] * wv;
    }
    float* hp = h + ((size_t)(b * N + n0 + wid * 4)) * D + d;
#pragma unroll
    for (int j = 0; j < 4; ++j) hp[(size_t)j * D] = fmaxf(acc[j], 0.f);
}

// ---------------- hW = relu(h@Wl) -> bf16 hi/lo planes in B-frag order; t1,t2 ----------------
__global__ __launch_bounds__(256) void k_hw(const float* __restrict__ h,
                                            const float* __restrict__ Wl,
                                            const float* __restrict__ a1,
                                            const float* __restrict__ a2,
                                            unsigned short* __restrict__ hWhi,
                                            unsigned short* __restrict__ hWlo,
                                            float* __restrict__ t1,
                                            float* __restrict__ t2) {
    int b = blockIdx.x >> 6, n0 = (blockIdx.x & 63) << 4;
    int t = threadIdx.x;
    __shared__ float wls[D * D];   // 16KB
    __shared__ float hs[16 * D];   // 4KB
    for (int j = t; j < D * D / 4; j += 256)
        ((float4*)wls)[j] = ((const float4*)Wl)[j];
    const float* hp = h + ((size_t)(b * N + n0)) * D;
    if (t < 16 * D / 4) ((float4*)hs)[t] = ((const float4*)hp)[t];
    __syncthreads();
    int d = t & 63, wid = t >> 6;
    float acc[4] = {0.f, 0.f, 0.f, 0.f};
    for (int k = 0; k < D; ++k) {
        float wv = wls[k * D + d];
#pragma unroll
        for (int j = 0; j < 4; ++j) acc[j] += hs[(wid * 4 + j) * D + k] * wv;
    }
    float a1d = a1[d], a2d = a2[d];

    float v[4];
    unsigned short vh[4], vl[4];
#pragma unroll
    for (int j = 0; j < 4; ++j) {
        v[j] = fmaxf(acc[j], 0.f);
        vh[j] = f2bf_rne(v[j]);
        vl[j] = f2bf_rne(v[j] - bf2f(vh[j]));
    }
    {
        int m0 = n0 + wid * 4;
        int kb = m0 >> 5, i0 = m0 & 7;
        int lb = ((m0 >> 3) & 3) * 16 + (d & 15), dt = d >> 4;
        size_t off = ((size_t)b * (N * D)) + ((kb * 4 + dt) * 64 + lb) * 8 + i0;
        uint2 hpack, lpack;
        hpack.x = (unsigned int)vh[0] | ((unsigned int)vh[1] << 16);
        hpack.y = (unsigned int)vh[2] | ((unsigned int)vh[3] << 16);
        lpack.x = (unsigned int)vl[0] | ((unsigned int)vl[1] << 16);
        lpack.y = (unsigned int)vl[2] | ((unsigned int)vl[3] << 16);
        *(uint2*)(hWhi + off) = hpack;
        *(uint2*)(hWlo + off) = lpack;
    }
#pragma unroll
    for (int j = 0; j < 4; ++j) {
        float p1 = v[j] * a1d, p2 = v[j] * a2d;
#pragma unroll
        for (int o = 32; o > 0; o >>= 1) {
            p1 += __shfl_down(p1, o);
            p2 += __shfl_down(p2, o);
        }
        if (d == 0) { t1[b * N + n0 + wid * 4 + j] = p1; t2[b * N + n0 + wid * 4 + j] = p2; }
    }
}

// ---------------- fused attention: 16 rows/block, w born in A-frag regs ----------------
// (256,4): R12 proved (256,3) costs +1.9us/dispatch -> TLP-sensitive; keep 4 blocks/CU.
__global__ __launch_bounds__(256, 4) void k_att(
    const unsigned short* __restrict__ hWhi, const unsigned short* __restrict__ hWlo,
    const float* __restrict__ t1, const float* __restrict__ t2,
    const unsigned long long* __restrict__ packA,
    const float* __restrict__ root_list, int ridx, float* __restrict__ h)
{
    int vb = (blockIdx.x & 7) * 128 + (blockIdx.x >> 3);   // XCD swizzle (1024 blocks)
    int b  = vb >> 6;
    int n0 = (vb & 63) << 4;
    int t = threadIdx.x, lane = t & 63, wid = t >> 6;

    __shared__ float t2s[N];               // 4KB
    __shared__ float redsum[4][16];
    __shared__ float invs[16];
    __shared__ float4v part[4][4][64];     // 16KB: [wid][dt][lane]

    ((float4v*)t2s)[t] = ((const float4v*)(t2 + b * N))[t];
    __syncthreads();

    int r  = lane & 15;
    int qg = wid * 4 + (lane >> 4);        // 0..15: global k-subgroup within a pass
    int n  = n0 + r;
    float t1v = t1[b * N + n];
    const unsigned long long* prow = packA + ((size_t)(b * N + n)) * 16;
    const short8v* BH = (const short8v*)(hWhi + (size_t)b * (N * D));
    const short8v* BL = (const short8v*)(hWlo + (size_t)b * (N * D));

    float4v acc0 = {0,0,0,0}, acc1 = {0,0,0,0}, acc2 = {0,0,0,0}, acc3 = {0,0,0,0};
    float lsum = 0.f;

#pragma unroll 2   // cap unroll: full 8x hoists 64 B-loads -> VGPR blowup
    for (int p = 0; p < 8; ++p) {
        int kb = p * 4 + wid;              // this wave's 32-wide k-block
        int bi = (kb * 4) * 64 + lane;
        short8v bh0 = BH[bi], bh1 = BH[bi + 64], bh2 = BH[bi + 128], bh3 = BH[bi + 192];
        short8v bl0 = BL[bi], bl1 = BL[bi + 64], bl2 = BL[bi + 128], bl3 = BL[bi + 192];

        unsigned long long word = prow[p * 2 + (qg >> 3)];
        unsigned int mbyte = (unsigned int)(word >> ((qg & 7) * 8)) & 0xFFu;

        const float* t2p = t2s + p * 128 + qg * 8;
        float4v ta = ((const float4v*)t2p)[0];
        float4v tb = ((const float4v*)t2p)[1];

        float wv[8];
#pragma unroll
        for (int i = 0; i < 8; ++i) {
            float t2v = (i < 4) ? ta[i & 3] : tb[i & 3];
            float e = ((mbyte >> i) & 1u) ? fmaxf(t1v + t2v, 0.f) : 0.f;
            float w = __expf(e);
            wv[i] = w;
            lsum += w;
        }

        AFrag fh, fl;
#pragma unroll
        for (int i = 0; i < 4; ++i)
            split_pair(wv[2 * i], wv[2 * i + 1], fh.u[i], fl.u[i]);

        acc0 = __builtin_amdgcn_mfma_f32_16x16x32_bf16(fh.s, bh0, acc0, 0, 0, 0);
        acc0 = __builtin_amdgcn_mfma_f32_16x16x32_bf16(fh.s, bl0, acc0, 0, 0, 0);
        acc0 = __builtin_amdgcn_mfma_f32_16x16x32_bf16(fl.s, bh0, acc0, 0, 0, 0);
        acc1 = __builtin_amdgcn_mfma_f32_16x16x32_bf16(fh.s, bh1, acc1, 0, 0, 0);
        acc1 = __builtin_amdgcn_mfma_f32_16x16x32_bf16(fh.s, bl1, acc1, 0, 0, 0);
        acc1 = __builtin_amdgcn_mfma_f32_16x16x32_bf16(fl.s, bh1, acc1, 0, 0, 0);
        acc2 = __builtin_amdgcn_mfma_f32_16x16x32_bf16(fh.s, bh2, acc2, 0, 0, 0);
        acc2 = __builtin_amdgcn_mfma_f32_16x16x32_bf16(fh.s, bl2, acc2, 0, 0, 0);
        acc2 = __builtin_amdgcn_mfma_f32_16x16x32_bf16(fl.s, bh2, acc2, 0, 0, 0);
        acc3 = __builtin_amdgcn_mfma_f32_16x16x32_bf16(fh.s, bh3, acc3, 0, 0, 0);
        acc3 = __builtin_amdgcn_mfma_f32_16x16x32_bf16(fh.s, bl3, acc3, 0, 0, 0);
        acc3 = __builtin_amdgcn_mfma_f32_16x16x32_bf16(fl.s, bh3, acc3, 0, 0, 0);
    }

    // per-row softmax denominators: lanes {l, l^16, l^32, l^48} share a row
    lsum += __shfl_xor(lsum, 16);
    lsum += __shfl_xor(lsum, 32);
    if (lane < 16) redsum[wid][lane] = lsum;

    part[wid][0][lane] = acc0;
    part[wid][1][lane] = acc1;
    part[wid][2][lane] = acc2;
    part[wid][3][lane] = acc3;
    __syncthreads();
    if (t < 16) invs[t] = 1.0f / (redsum[0][t] + redsum[1][t] + redsum[2][t] + redsum[3][t]);
    __syncthreads();

    // reduce 4 wave-partials; C mapping: col=lane&15, row=(lane>>4)*4+reg
    int c = t & 63, rg = t >> 6;
    int ls = rg * 16 + (c & 15), dt = c >> 4;
    float4v s = part[0][dt][ls] + part[1][dt][ls] + part[2][dt][ls] + part[3][dt][ls];
    const float* rl = root_list + ((size_t)b * DEPTH + ridx) * N;
#pragma unroll
    for (int reg = 0; reg < 4; ++reg) {
        int rr = rg * 4 + reg;
        if (rl[n0 + rr] > 0.f)
            h[((size_t)(b * N + n0 + rr)) * D + c] = s[reg] * invs[rr];
    }
}

// ---------------- pooling dot: w[b][n] = root>0 ? relu(h.P) : -9e15 ----------------
__global__ __launch_bounds__(256) void k_dotw(const float* __restrict__ h,
                                              const float* __restrict__ root_list,
                                              const float* __restrict__ P,
                                              float* __restrict__ wg) {
    int b = blockIdx.x >> 4, n0 = (blockIdx.x & 15) << 6;
    int t = threadIdx.x;
    int r = n0 + (t >> 2), sub = t & 3;
    const float4* hp = (const float4*)(h + ((size_t)(b * N + r)) * D + sub * 16);
    const float4* pp = (const float4*)(P + sub * 16);
    float s = 0.f;
#pragma unroll
    for (int i = 0; i < 4; ++i) {
        float4 hv = hp[i], pv = pp[i];
        s += hv.x * pv.x + hv.y * pv.y + hv.z * pv.z + hv.w * pv.w;
    }
    s += __shfl_xor(s, 1);
    s += __shfl_xor(s, 2);
    if (sub == 0) {
        float rv = root_list[((size_t)b * DEPTH + 1) * N + r];
        wg[b * N + r] = (rv > 0.f) ? fmaxf(s, 0.f) : -9e15f;
    }
}

// ---------------- softmax + weighted sum + BN-MLP, 1024 threads/batch ----------------
__global__ __launch_bounds__(1024) void k_pool2(const float* __restrict__ h,
                       const float* __restrict__ wg,
                       const float* __restrict__ pW1, const float* __restrict__ pb1,
                       const float* __restrict__ g1, const float* __restrict__ be1,
                       const float* __restrict__ m1, const float* __restrict__ v1,
                       const float* __restrict__ pW2, const float* __restrict__ pb2,
                       const float* __restrict__ g2, const float* __restrict__ be2,
                       const float* __restrict__ m2, const float* __restrict__ v2,
                       const float* __restrict__ pW3, const float* __restrict__ pb3,
                       float* __restrict__ out) {
    int b = blockIdx.x, t = threadIdx.x, lane = t & 63, wid = t >> 6;  // 16 waves
    __shared__ float ws[N];
    __shared__ float red[16];
    __shared__ float part[16][D];
    __shared__ float od[D];
    __shared__ float x1[128];
    __shared__ float x2[64];
    __shared__ float lg[2];

    const float* hb = h + (size_t)b * N * D;
    float sc = wg[b * N + t];

    float lmax = sc;
#pragma unroll
    for (int o = 32; o > 0; o >>= 1) lmax = fmaxf(lmax, __shfl_xor(lmax, o));
    if (lane == 0) red[wid] = lmax;
    __syncthreads();
    float bmax = red[0];
#pragma unroll
    for (int k = 1; k < 16; ++k) bmax = fmaxf(bmax, red[k]);
    __syncthreads();

    float e = __expf(sc - bmax);
    ws[t] = e;
    float lsumv = e;
#pragma unroll
    for (int o = 32; o > 0; o >>= 1) lsumv += __shfl_xor(lsumv, o);
    if (lane == 0) red[wid] = lsumv;
    __syncthreads();
    float bsum = 0.f;
#pragma unroll
    for (int k = 0; k < 16; ++k) bsum += red[k];
    float inv = 1.0f / bsum;

    float acc = 0.f;
    for (int n = wid * 64; n < wid * 64 + 64; ++n) acc += ws[n] * hb[(size_t)n * D + lane];
    part[wid][lane] = acc;
    __syncthreads();
    if (t < D) {
        float s = 0.f;
#pragma unroll
        for (int k = 0; k < 16; ++k) s += part[k][t];
        od[t] = s * inv;
    }
    __syncthreads();

    if (t < 128) {
        float s = pb1[t];
#pragma unroll
        for (int k = 0; k < D; ++k) s += od[k] * pW1[k * 128 + t];
        s = (s - m1[t]) * rsqrtf(v1[t] + BN_EPS) * g1[t] + be1[t];
        x1[t] = fmaxf(s, 0.f);
    }
    __syncthreads();
    if (t < 64) {
        float s = pb2[t];
#pragma unroll
        for (int k = 0; k < 128; ++k) s += x1[k] * pW2[k * 64 + t];
        s = (s - m2[t]) * rsqrtf(v2[t] + BN_EPS) * g2[t] + be2[t];
        x2[t] = fmaxf(s, 0.f);
    }
    __syncthreads();
    if (t < 2) {
        float s = pb3[t];
#pragma unroll
        for (int k = 0; k < 64; ++k) s += x2[k] * pW3[k * 2 + t];
        lg[t] = fmaxf(s, 0.f);
    }
    __syncthreads();
    if (t < 2) {
        float mm = fmaxf(lg[0], lg[1]);
        float e0 = __expf(lg[0] - mm), e1 = __expf(lg[1] - mm);
        out[b * 2 + t] = ((t == 0) ? e0 : e1) / (e0 + e1);
    }
}

extern "C" void kernel_launch(void* const* d_in, const int* in_sizes, int n_in,
                              void* d_out, int out_size, void* d_ws, size_t ws_size,
                              hipStream_t stream) {
    const int*   adj = (const int*)d_in[0];
    const float* X   = (const float*)d_in[1];
    const float* rl  = (const float*)d_in[2];
    const float* W0  = (const float*)d_in[3];
    const float* Wl  = (const float*)d_in[4];
    const float* a1l = (const float*)d_in[5];
    const float* a2l = (const float*)d_in[6];
    const float* P   = (const float*)d_in[7];
    const float* pW1 = (const float*)d_in[8];
    const float* pb1 = (const float*)d_in[9];
    const float* g1  = (const float*)d_in[10];
    const float* be1 = (const float*)d_in[11];
    const float* m1  = (const float*)d_in[12];
    const float* v1  = (const float*)d_in[13];
    const float* pW2 = (const float*)d_in[14];
    const float* pb2 = (const float*)d_in[15];
    const float* g2  = (const float*)d_in[16];
    const float* be2 = (const float*)d_in[17];
    const float* m2  = (const float*)d_in[18];
    const float* v2  = (const float*)d_in[19];
    const float* pW3 = (const float*)d_in[20];
    const float* pb3 = (const float*)d_in[21];
    float* out = (float*)d_out;

    // ws layout: 10,616,832 B total — footprint proven since R3
    float*          h    = (float*)d_ws;                                   // 4MB
    unsigned short* hWhi = (unsigned short*)(h + (size_t)B * N * D);       // 2MB
    unsigned short* hWlo = hWhi + (size_t)B * N * D;                       // 2MB
    float*          t1   = (float*)(hWlo + (size_t)B * N * D);             // 64KB
    float*          t2   = t1 + B * N;                                     // 64KB
    unsigned long long* packA = (unsigned long long*)(t2 + B * N);         // 2MB
    float*          wg   = t1;   // t1 dead after layer loop; reuse for pooling scores

    k_pre<<<4096 + B * 64, 256, 0, stream>>>(adj, (unsigned short*)packA, X, W0, h);
    for (int i = 0; i < DEPTH - 1; ++i) {
        k_hw<<<B * 64, 256, 0, stream>>>(h, Wl + i * D * D, a1l + i * D, a2l + i * D,
                                         hWhi, hWlo, t1, t2);
        k_att<<<B * 64, 256, 0, stream>>>(hWhi, hWlo, t1, t2, packA, rl,
                                          DEPTH - 1 - i, h);
    }
    k_dotw<<<B * 16, 256, 0, stream>>>(h, rl, P, wg);
    k_pool2<<<B, 1024, 0, stream>>>(h, wg, pW1, pb1, g1, be1, m1, v1,
                                    pW2, pb2, g2, be2, m2, v2, pW3, pb3, out);
}

// Round 14
// 220.838 us; speedup vs baseline: 1.0526x; 1.0282x over previous
//
#include <hip/hip_runtime.h>
#include <hip/hip_bf16.h>
#include <math.h>

#define B 16
#define N 1024
#define F_IN 80
#define D 64
#define DEPTH 4
#define BN_EPS 1e-5f

typedef __attribute__((ext_vector_type(8))) short  short8v;
typedef __attribute__((ext_vector_type(4))) float  float4v;

union AFrag { unsigned int u[4]; short8v s; };

__device__ __forceinline__ unsigned short f2bf_rne(float x) {
    unsigned int u = __float_as_uint(x);
    unsigned int r = u + 0x7FFFu + ((u >> 16) & 1u);
    return (unsigned short)(r >> 16);
}
__device__ __forceinline__ float bf2f(unsigned short b) {
    return __uint_as_float(((unsigned int)b) << 16);
}
// trunc-split a pair of positives into packed bf16 hi / residual-lo words.
__device__ __forceinline__ void split_pair(float w0, float w1,
                                           unsigned int& hi, unsigned int& lo) {
    unsigned int u0 = __float_as_uint(w0), u1 = __float_as_uint(w1);
    unsigned int h0 = u0 & 0xFFFF0000u,   h1 = u1 & 0xFFFF0000u;
    hi = (h0 >> 16) | h1;
    float r0 = w0 - __uint_as_float(h0);
    float r1 = w1 - __uint_as_float(h1);
    lo = (__float_as_uint(r0) >> 16) | (__float_as_uint(r1) & 0xFFFF0000u);
}

// ---------------- fused: adj bit-pack (blocks 0..4095) + h0 (blocks 4096..5119) ----------------
__global__ __launch_bounds__(256) void k_pre(const int* __restrict__ adj,
                                             unsigned short* __restrict__ packS,
                                             const float* __restrict__ X,
                                             const float* __restrict__ W0,
                                             float* __restrict__ h) {
    if (blockIdx.x < 4096) {
        int gid = blockIdx.x * 256 + threadIdx.x;      // 0 .. B*N*N/16-1
        const int4* ap = (const int4*)adj + (size_t)gid * 4;
        unsigned int m = 0;
#pragma unroll
        for (int i = 0; i < 4; ++i) {
            int4 v = ap[i];
            m |= (unsigned int)(v.x > 0) << (i * 4 + 0);
            m |= (unsigned int)(v.y > 0) << (i * 4 + 1);
            m |= (unsigned int)(v.z > 0) << (i * 4 + 2);
            m |= (unsigned int)(v.w > 0) << (i * 4 + 3);
        }
        packS[gid] = (unsigned short)m;
        return;
    }
    int bid = blockIdx.x - 4096;
    int b = bid >> 6, n0 = (bid & 63) << 4;
    int t = threadIdx.x;
    __shared__ float w0s[F_IN * D];   // 20KB
    __shared__ float xs[16 * F_IN];   // 5KB
    for (int j = t; j < F_IN * D / 4; j += 256)
        ((float4*)w0s)[j] = ((const float4*)W0)[j];
    const float* xp = X + ((size_t)(b * N + n0)) * F_IN;
    for (int j = t; j < 16 * F_IN / 4; j += 256)
        ((float4*)xs)[j] = ((const float4*)xp)[j];
    __syncthreads();
    int d = t & 63, wid = t >> 6;
    float acc[4] = {0.f, 0.f, 0.f, 0.f};
    for (int f = 0; f < F_IN; ++f) {
        float wv = w0s[f * D + d];
#pragma unroll
        for (int j = 0; j < 4; ++j) acc[j] += xs[(wid * 4 + j) * F_IN + f] * wv;
    }
    float* hp = h + ((size_t)(b * N + n0 + wid * 4)) * D + d;
#pragma unroll
    for (int j = 0; j < 4; ++j) hp[(size_t)j * D] = fmaxf(acc[j], 0.f);
}

// ---------------- hW = relu(h@Wl) -> bf16 hi/lo planes in B-frag order; t1,t2 ----------------
__global__ __launch_bounds__(256) void k_hw(const float* __restrict__ h,
                                            const float* __restrict__ Wl,
                                            const float* __restrict__ a1,
                                            const float* __restrict__ a2,
                                            unsigned short* __restrict__ hWhi,
                                            unsigned short* __restrict__ hWlo,
                                            float* __restrict__ t1,
                                            float* __restrict__ t2) {
    int b = blockIdx.x >> 6, n0 = (blockIdx.x & 63) << 4;
    int t = threadIdx.x;
    __shared__ float wls[D * D];   // 16KB
    __shared__ float hs[16 * D];   // 4KB
    for (int j = t; j < D * D / 4; j += 256)
        ((float4*)wls)[j] = ((const float4*)Wl)[j];
    const float* hp = h + ((size_t)(b * N + n0)) * D;
    if (t < 16 * D / 4) ((float4*)hs)[t] = ((const float4*)hp)[t];
    __syncthreads();
    int d = t & 63, wid = t >> 6;
    float acc[4] = {0.f, 0.f, 0.f, 0.f};
    for (int k = 0; k < D; ++k) {
        float wv = wls[k * D + d];
#pragma unroll
        for (int j = 0; j < 4; ++j) acc[j] += hs[(wid * 4 + j) * D + k] * wv;
    }
    float a1d = a1[d], a2d = a2[d];

    float v[4];
    unsigned short vh[4], vl[4];
#pragma unroll
    for (int j = 0; j < 4; ++j) {
        v[j] = fmaxf(acc[j], 0.f);
        vh[j] = f2bf_rne(v[j]);
        vl[j] = f2bf_rne(v[j] - bf2f(vh[j]));
    }
    {
        int m0 = n0 + wid * 4;
        int kb = m0 >> 5, i0 = m0 & 7;
        int lb = ((m0 >> 3) & 3) * 16 + (d & 15), dt = d >> 4;
        size_t off = ((size_t)b * (N * D)) + ((kb * 4 + dt) * 64 + lb) * 8 + i0;
        uint2 hpack, lpack;
        hpack.x = (unsigned int)vh[0] | ((unsigned int)vh[1] << 16);
        hpack.y = (unsigned int)vh[2] | ((unsigned int)vh[3] << 16);
        lpack.x = (unsigned int)vl[0] | ((unsigned int)vl[1] << 16);
        lpack.y = (unsigned int)vl[2] | ((unsigned int)vl[3] << 16);
        *(uint2*)(hWhi + off) = hpack;
        *(uint2*)(hWlo + off) = lpack;
    }
#pragma unroll
    for (int j = 0; j < 4; ++j) {
        float p1 = v[j] * a1d, p2 = v[j] * a2d;
#pragma unroll
        for (int o = 32; o > 0; o >>= 1) {
            p1 += __shfl_down(p1, o);
            p2 += __shfl_down(p2, o);
        }
        if (d == 0) { t1[b * N + n0 + wid * 4 + j] = p1; t2[b * N + n0 + wid * 4 + j] = p2; }
    }
}

// ---------------- fused attention: 32 rows/block (halved L2 B-panel traffic) ----------------
// R13 analysis: 16-row blocks re-read the 256KB hi+lo panel 64x/batch -> ~1MB/CU L2 floor.
// 32 rows/block shares every B-load across 2 A-fragment sets. 512 blocks, 2 blocks/CU.
__global__ __launch_bounds__(256, 2) void k_att(
    const unsigned short* __restrict__ hWhi, const unsigned short* __restrict__ hWlo,
    const float* __restrict__ t1, const float* __restrict__ t2,
    const unsigned long long* __restrict__ packA,
    const float* __restrict__ root_list, int ridx, float* __restrict__ h)
{
    int vb = (blockIdx.x & 7) * 64 + (blockIdx.x >> 3);   // XCD swizzle (512 blocks)
    int b  = vb >> 5;
    int n0 = (vb & 31) << 5;
    int t = threadIdx.x, lane = t & 63, wid = t >> 6;

    __shared__ float t2s[N];                 // 4KB
    __shared__ float redsum[2][4][16];
    __shared__ float invs[32];
    __shared__ float4v part[2][4][4][64];    // 32KB: [set][wid][dt][lane]

    ((float4v*)t2s)[t] = ((const float4v*)(t2 + b * N))[t];
    __syncthreads();

    int r  = lane & 15;
    int qg = wid * 4 + (lane >> 4);          // 0..15: k-subgroup within a pass
    int nA = n0 + r, nB = nA + 16;
    float t1vA = t1[b * N + nA];
    float t1vB = t1[b * N + nB];
    const unsigned long long* prowA = packA + ((size_t)(b * N + nA)) * 16;
    const unsigned long long* prowB = packA + ((size_t)(b * N + nB)) * 16;
    const short8v* BH = (const short8v*)(hWhi + (size_t)b * (N * D));
    const short8v* BL = (const short8v*)(hWlo + (size_t)b * (N * D));

    float4v a0 = {0,0,0,0}, a1v = {0,0,0,0}, a2v = {0,0,0,0}, a3 = {0,0,0,0};
    float4v b0 = {0,0,0,0}, b1v = {0,0,0,0}, b2v = {0,0,0,0}, b3 = {0,0,0,0};
    float lsumA = 0.f, lsumB = 0.f;

#pragma unroll 2
    for (int p = 0; p < 8; ++p) {
        int kb = p * 4 + wid;
        int bi = (kb * 4) * 64 + lane;
        short8v bh0 = BH[bi], bh1 = BH[bi + 64], bh2 = BH[bi + 128], bh3 = BH[bi + 192];
        short8v bl0 = BL[bi], bl1 = BL[bi + 64], bl2 = BL[bi + 128], bl3 = BL[bi + 192];

        unsigned long long wordA = prowA[p * 2 + (qg >> 3)];
        unsigned long long wordB = prowB[p * 2 + (qg >> 3)];
        unsigned int mbA = (unsigned int)(wordA >> ((qg & 7) * 8)) & 0xFFu;
        unsigned int mbB = (unsigned int)(wordB >> ((qg & 7) * 8)) & 0xFFu;

        const float* t2p = t2s + p * 128 + qg * 8;
        float4v ta = ((const float4v*)t2p)[0];
        float4v tb = ((const float4v*)t2p)[1];

        float wvA[8], wvB[8];
#pragma unroll
        for (int i = 0; i < 8; ++i) {
            float t2v = (i < 4) ? ta[i & 3] : tb[i & 3];
            float eA = ((mbA >> i) & 1u) ? fmaxf(t1vA + t2v, 0.f) : 0.f;
            float eB = ((mbB >> i) & 1u) ? fmaxf(t1vB + t2v, 0.f) : 0.f;
            float wA = __expf(eA), wB = __expf(eB);
            wvA[i] = wA; lsumA += wA;
            wvB[i] = wB; lsumB += wB;
        }

        AFrag fhA, flA, fhB, flB;
#pragma unroll
        for (int i = 0; i < 4; ++i) {
            split_pair(wvA[2 * i], wvA[2 * i + 1], fhA.u[i], flA.u[i]);
            split_pair(wvB[2 * i], wvB[2 * i + 1], fhB.u[i], flB.u[i]);
        }

        a0 = __builtin_amdgcn_mfma_f32_16x16x32_bf16(fhA.s, bh0, a0, 0, 0, 0);
        a0 = __builtin_amdgcn_mfma_f32_16x16x32_bf16(fhA.s, bl0, a0, 0, 0, 0);
        a0 = __builtin_amdgcn_mfma_f32_16x16x32_bf16(flA.s, bh0, a0, 0, 0, 0);
        b0 = __builtin_amdgcn_mfma_f32_16x16x32_bf16(fhB.s, bh0, b0, 0, 0, 0);
        b0 = __builtin_amdgcn_mfma_f32_16x16x32_bf16(fhB.s, bl0, b0, 0, 0, 0);
        b0 = __builtin_amdgcn_mfma_f32_16x16x32_bf16(flB.s, bh0, b0, 0, 0, 0);
        a1v = __builtin_amdgcn_mfma_f32_16x16x32_bf16(fhA.s, bh1, a1v, 0, 0, 0);
        a1v = __builtin_amdgcn_mfma_f32_16x16x32_bf16(fhA.s, bl1, a1v, 0, 0, 0);
        a1v = __builtin_amdgcn_mfma_f32_16x16x32_bf16(flA.s, bh1, a1v, 0, 0, 0);
        b1v = __builtin_amdgcn_mfma_f32_16x16x32_bf16(fhB.s, bh1, b1v, 0, 0, 0);
        b1v = __builtin_amdgcn_mfma_f32_16x16x32_bf16(fhB.s, bl1, b1v, 0, 0, 0);
        b1v = __builtin_amdgcn_mfma_f32_16x16x32_bf16(flB.s, bh1, b1v, 0, 0, 0);
        a2v = __builtin_amdgcn_mfma_f32_16x16x32_bf16(fhA.s, bh2, a2v, 0, 0, 0);
        a2v = __builtin_amdgcn_mfma_f32_16x16x32_bf16(fhA.s, bl2, a2v, 0, 0, 0);
        a2v = __builtin_amdgcn_mfma_f32_16x16x32_bf16(flA.s, bh2, a2v, 0, 0, 0);
        b2v = __builtin_amdgcn_mfma_f32_16x16x32_bf16(fhB.s, bh2, b2v, 0, 0, 0);
        b2v = __builtin_amdgcn_mfma_f32_16x16x32_bf16(fhB.s, bl2, b2v, 0, 0, 0);
        b2v = __builtin_amdgcn_mfma_f32_16x16x32_bf16(flB.s, bh2, b2v, 0, 0, 0);
        a3 = __builtin_amdgcn_mfma_f32_16x16x32_bf16(fhA.s, bh3, a3, 0, 0, 0);
        a3 = __builtin_amdgcn_mfma_f32_16x16x32_bf16(fhA.s, bl3, a3, 0, 0, 0);
        a3 = __builtin_amdgcn_mfma_f32_16x16x32_bf16(flA.s, bh3, a3, 0, 0, 0);
        b3 = __builtin_amdgcn_mfma_f32_16x16x32_bf16(fhB.s, bh3, b3, 0, 0, 0);
        b3 = __builtin_amdgcn_mfma_f32_16x16x32_bf16(fhB.s, bl3, b3, 0, 0, 0);
        b3 = __builtin_amdgcn_mfma_f32_16x16x32_bf16(flB.s, bh3, b3, 0, 0, 0);
    }

    // per-row softmax denominators: lanes {l, l^16, l^32, l^48} share a row
    lsumA += __shfl_xor(lsumA, 16);
    lsumA += __shfl_xor(lsumA, 32);
    lsumB += __shfl_xor(lsumB, 16);
    lsumB += __shfl_xor(lsumB, 32);
    if (lane < 16) { redsum[0][wid][lane] = lsumA; redsum[1][wid][lane] = lsumB; }

    part[0][wid][0][lane] = a0;
    part[0][wid][1][lane] = a1v;
    part[0][wid][2][lane] = a2v;
    part[0][wid][3][lane] = a3;
    part[1][wid][0][lane] = b0;
    part[1][wid][1][lane] = b1v;
    part[1][wid][2][lane] = b2v;
    part[1][wid][3][lane] = b3;
    __syncthreads();
    if (t < 32) {
        int s = t >> 4, rr = t & 15;
        invs[s * 16 + rr] = 1.0f / (redsum[s][0][rr] + redsum[s][1][rr] +
                                    redsum[s][2][rr] + redsum[s][3][rr]);
    }
    __syncthreads();

    // reduce 4 wave-partials; C mapping: col=lane&15, row=(lane>>4)*4+reg
    int c = t & 63, rg = t >> 6;
    int ls = rg * 16 + (c & 15), dt = c >> 4;
    const float* rl = root_list + ((size_t)b * DEPTH + ridx) * N;
#pragma unroll
    for (int s = 0; s < 2; ++s) {
        float4v sv = part[s][0][dt][ls] + part[s][1][dt][ls] +
                     part[s][2][dt][ls] + part[s][3][dt][ls];
#pragma unroll
        for (int reg = 0; reg < 4; ++reg) {
            int rr = rg * 4 + reg;          // row within set
            int n = n0 + s * 16 + rr;
            if (rl[n] > 0.f)
                h[((size_t)(b * N + n)) * D + c] = sv[reg] * invs[s * 16 + rr];
        }
    }
}

// ---------------- pooling dot: w[b][n] = root>0 ? relu(h.P) : -9e15 ----------------
__global__ __launch_bounds__(256) void k_dotw(const float* __restrict__ h,
                                              const float* __restrict__ root_list,
                                              const float* __restrict__ P,
                                              float* __restrict__ wg) {
    int b = blockIdx.x >> 4, n0 = (blockIdx.x & 15) << 6;
    int t = threadIdx.x;
    int r = n0 + (t >> 2), sub = t & 3;
    const float4* hp = (const float4*)(h + ((size_t)(b * N + r)) * D + sub * 16);
    const float4* pp = (const float4*)(P + sub * 16);
    float s = 0.f;
#pragma unroll
    for (int i = 0; i < 4; ++i) {
        float4 hv = hp[i], pv = pp[i];
        s += hv.x * pv.x + hv.y * pv.y + hv.z * pv.z + hv.w * pv.w;
    }
    s += __shfl_xor(s, 1);
    s += __shfl_xor(s, 2);
    if (sub == 0) {
        float rv = root_list[((size_t)b * DEPTH + 1) * N + r];
        wg[b * N + r] = (rv > 0.f) ? fmaxf(s, 0.f) : -9e15f;
    }
}

// ---------------- softmax + weighted sum + BN-MLP, 1024 threads/batch ----------------
__global__ __launch_bounds__(1024) void k_pool2(const float* __restrict__ h,
                       const float* __restrict__ wg,
                       const float* __restrict__ pW1, const float* __restrict__ pb1,
                       const float* __restrict__ g1, const float* __restrict__ be1,
                       const float* __restrict__ m1, const float* __restrict__ v1,
                       const float* __restrict__ pW2, const float* __restrict__ pb2,
                       const float* __restrict__ g2, const float* __restrict__ be2,
                       const float* __restrict__ m2, const float* __restrict__ v2,
                       const float* __restrict__ pW3, const float* __restrict__ pb3,
                       float* __restrict__ out) {
    int b = blockIdx.x, t = threadIdx.x, lane = t & 63, wid = t >> 6;  // 16 waves
    __shared__ float ws[N];
    __shared__ float red[16];
    __shared__ float part[16][D];
    __shared__ float od[D];
    __shared__ float x1[128];
    __shared__ float x2[64];
    __shared__ float lg[2];

    const float* hb = h + (size_t)b * N * D;
    float sc = wg[b * N + t];

    float lmax = sc;
#pragma unroll
    for (int o = 32; o > 0; o >>= 1) lmax = fmaxf(lmax, __shfl_xor(lmax, o));
    if (lane == 0) red[wid] = lmax;
    __syncthreads();
    float bmax = red[0];
#pragma unroll
    for (int k = 1; k < 16; ++k) bmax = fmaxf(bmax, red[k]);
    __syncthreads();

    float e = __expf(sc - bmax);
    ws[t] = e;
    float lsumv = e;
#pragma unroll
    for (int o = 32; o > 0; o >>= 1) lsumv += __shfl_xor(lsumv, o);
    if (lane == 0) red[wid] = lsumv;
    __syncthreads();
    float bsum = 0.f;
#pragma unroll
    for (int k = 0; k < 16; ++k) bsum += red[k];
    float inv = 1.0f / bsum;

    float acc = 0.f;
    for (int n = wid * 64; n < wid * 64 + 64; ++n) acc += ws[n] * hb[(size_t)n * D + lane];
    part[wid][lane] = acc;
    __syncthreads();
    if (t < D) {
        float s = 0.f;
#pragma unroll
        for (int k = 0; k < 16; ++k) s += part[k][t];
        od[t] = s * inv;
    }
    __syncthreads();

    if (t < 128) {
        float s = pb1[t];
#pragma unroll
        for (int k = 0; k < D; ++k) s += od[k] * pW1[k * 128 + t];
        s = (s - m1[t]) * rsqrtf(v1[t] + BN_EPS) * g1[t] + be1[t];
        x1[t] = fmaxf(s, 0.f);
    }
    __syncthreads();
    if (t < 64) {
        float s = pb2[t];
#pragma unroll
        for (int k = 0; k < 128; ++k) s += x1[k] * pW2[k * 64 + t];
        s = (s - m2[t]) * rsqrtf(v2[t] + BN_EPS) * g2[t] + be2[t];
        x2[t] = fmaxf(s, 0.f);
    }
    __syncthreads();
    if (t < 2) {
        float s = pb3[t];
#pragma unroll
        for (int k = 0; k < 64; ++k) s += x2[k] * pW3[k * 2 + t];
        lg[t] = fmaxf(s, 0.f);
    }
    __syncthreads();
    if (t < 2) {
        float mm = fmaxf(lg[0], lg[1]);
        float e0 = __expf(lg[0] - mm), e1 = __expf(lg[1] - mm);
        out[b * 2 + t] = ((t == 0) ? e0 : e1) / (e0 + e1);
    }
}

extern "C" void kernel_launch(void* const* d_in, const int* in_sizes, int n_in,
                              void* d_out, int out_size, void* d_ws, size_t ws_size,
                              hipStream_t stream) {
    const int*   adj = (const int*)d_in[0];
    const float* X   = (const float*)d_in[1];
    const float* rl  = (const float*)d_in[2];
    const float* W0  = (const float*)d_in[3];
    const float* Wl  = (const float*)d_in[4];
    const float* a1l = (const float*)d_in[5];
    const float* a2l = (const float*)d_in[6];
    const float* P   = (const float*)d_in[7];
    const float* pW1 = (const float*)d_in[8];
    const float* pb1 = (const float*)d_in[9];
    const float* g1  = (const float*)d_in[10];
    const float* be1 = (const float*)d_in[11];
    const float* m1  = (const float*)d_in[12];
    const float* v1  = (const float*)d_in[13];
    const float* pW2 = (const float*)d_in[14];
    const float* pb2 = (const float*)d_in[15];
    const float* g2  = (const float*)d_in[16];
    const float* be2 = (const float*)d_in[17];
    const float* m2  = (const float*)d_in[18];
    const float* v2  = (const float*)d_in[19];
    const float* pW3 = (const float*)d_in[20];
    const float* pb3 = (const float*)d_in[21];
    float* out = (float*)d_out;

    // ws layout: 10,616,832 B total — footprint proven since R3
    float*          h    = (float*)d_ws;                                   // 4MB
    unsigned short* hWhi = (unsigned short*)(h + (size_t)B * N * D);       // 2MB
    unsigned short* hWlo = hWhi + (size_t)B * N * D;                       // 2MB
    float*          t1   = (float*)(hWlo + (size_t)B * N * D);             // 64KB
    float*          t2   = t1 + B * N;                                     // 64KB
    unsigned long long* packA = (unsigned long long*)(t2 + B * N);         // 2MB
    float*          wg   = t1;   // t1 dead after layer loop; reuse for pooling scores

    k_pre<<<4096 + B * 64, 256, 0, stream>>>(adj, (unsigned short*)packA, X, W0, h);
    for (int i = 0; i < DEPTH - 1; ++i) {
        k_hw<<<B * 64, 256, 0, stream>>>(h, Wl + i * D * D, a1l + i * D, a2l + i * D,
                                         hWhi, hWlo, t1, t2);
        k_att<<<B * 32, 256, 0, stream>>>(hWhi, hWlo, t1, t2, packA, rl,
                                          DEPTH - 1 - i, h);
    }
    k_dotw<<<B * 16, 256, 0, stream>>>(h, rl, P, wg);
    k_pool2<<<B, 1024, 0, stream>>>(h, wg, pW1, pb1, g1, be1, m1, v1,
                                    pW2, pb2, g2, be2, m2, v2, pW3, pb3, out);
}